// Round 1
// baseline (494.008 us; speedup 1.0000x reference)
//
#include <hip/hip_runtime.h>

#define TT 5
#define HH 384
#define WW 384
#define CC 3
#define PS_ 7
#define WSR 4
#define NH_ 96
#define NW_ 96
#define NQ_ (TT*NH_*NW_)   // 46080
#define NCAND 243
#define KK 10

// One block (256 threads) per query.
__global__ __launch_bounds__(256) void nls_kernel(
    const float* __restrict__ vid,    // noisy [T,C,H,W]
    const float* __restrict__ fflow,  // [T,2,H,W], ch0=x/w, ch1=y/h
    const float* __restrict__ bflow,
    float* __restrict__ ws)           // [NQ_] per-query top-K sums
{
    const int q   = blockIdx.x;
    const int tid = threadIdx.x;
    const int t   = q / (NH_*NW_);
    const int rem = q % (NH_*NW_);
    const int hi  = (rem / NW_) * 4;
    const int wi  = (rem % NW_) * 4;

    __shared__ float qp[160];        // query patch [c][7][7]
    __shared__ float region[3*675];  // [di][c][15][15]
    __shared__ float dist[256];

    // Flow at the query point (wave-uniform loads, cached)
    const float ffx = fflow[((t*2+0)*HH + hi)*WW + wi];
    const float ffy = fflow[((t*2+1)*HH + hi)*WW + wi];
    const float bfx = bflow[((t*2+0)*HH + hi)*WW + wi];
    const float bfy = bflow[((t*2+1)*HH + hi)*WW + wi];

    // Per-dt candidate-window centers. dt order: [-1 (bflow), 0, +1 (fflow)]
    const int tj0 = (t-1 < 0) ? 0 : (t-1);
    const int tj2 = (t+1 > TT-1) ? (TT-1) : (t+1);
    const int bh0 = min(max(hi + (int)rintf(bfy), 0), HH-1);
    const int bw0 = min(max(wi + (int)rintf(bfx), 0), WW-1);
    const int bh2 = min(max(hi + (int)rintf(ffy), 0), HH-1);
    const int bw2 = min(max(wi + (int)rintf(ffx), 0), WW-1);
    const int rm0 = max(bh0-WSR, 0), cm0 = max(bw0-WSR, 0);
    const int rm1 = max(hi -WSR, 0), cm1 = max(wi -WSR, 0);
    const int rm2 = max(bh2-WSR, 0), cm2 = max(bw2-WSR, 0);

    // ---- Stage query patch (147 elems) ----
    if (tid < 147) {
        int c  = tid / 49;
        int dy = (tid % 49) / 7;
        int dx = tid % 7;
        int r  = min(hi + dy, HH-1);
        int cl = min(wi + dx, WW-1);
        qp[tid] = vid[((t*CC + c)*HH + r)*WW + cl];
    }
    // ---- Stage candidate regions: rows rm..rm+14, cols cm..cm+14 (clamped) ----
    for (int i = tid; i < 3*675; i += 256) {
        int d  = i / 675;
        int e  = i % 675;
        int c  = e / 225;
        int r  = (e % 225) / 15;
        int cl = e % 15;
        int tjd = (d==0) ? tj0 : ((d==1) ? t   : tj2);
        int rm  = (d==0) ? rm0 : ((d==1) ? rm1 : rm2);
        int cm  = (d==0) ? cm0 : ((d==1) ? cm1 : cm2);
        int row = min(rm + r,  HH-1);
        int col = min(cm + cl, WW-1);
        region[i] = vid[((tjd*CC + c)*HH + row)*WW + col];
    }
    __syncthreads();

    // ---- Each of 243 threads: one candidate distance ----
    float acc = 0.0f;
    if (tid < NCAND) {
        int di = tid / 81;
        int s  = tid % 81;
        int sy = s / 9 - WSR;
        int sx = s % 9 - WSR;
        int bhd = (di==0) ? bh0 : ((di==1) ? hi : bh2);
        int bwd = (di==0) ? bw0 : ((di==1) ? wi : bw2);
        int rm  = (di==0) ? rm0 : ((di==1) ? rm1 : rm2);
        int cm  = (di==0) ? cm0 : ((di==1) ? cm1 : cm2);
        int hj = min(max(bhd + sy, 0), HH-1);   // clamp center first (ref semantics)
        int wj = min(max(bwd + sx, 0), WW-1);
        const float* regp = &region[di*675];
        if (hj + (PS_-1) <= HH-1 && wj + (PS_-1) <= WW-1) {
            // interior: all offsets compile-time (enables ds_read2 fusion)
            int base = (hj - rm)*15 + (wj - cm);
            #pragma unroll
            for (int c = 0; c < CC; c++)
              #pragma unroll
              for (int dy = 0; dy < PS_; dy++)
                #pragma unroll
                for (int dx = 0; dx < PS_; dx++) {
                    float cv = regp[c*225 + base + dy*15 + dx];
                    float qv = qp[c*49 + dy*7 + dx];
                    float dd = qv - cv;
                    acc = fmaf(dd, dd, acc);
                }
        } else {
            // border: per-element clamp (patch clamps relative to clamped center)
            #pragma unroll
            for (int c = 0; c < CC; c++)
              #pragma unroll
              for (int dy = 0; dy < PS_; dy++) {
                int rr = min(hj + dy, HH-1) - rm;
                #pragma unroll
                for (int dx = 0; dx < PS_; dx++) {
                    int cc2 = min(wj + dx, WW-1) - cm;
                    float cv = regp[c*225 + rr*15 + cc2];
                    float qv = qp[c*49 + dy*7 + dx];
                    float dd = qv - cv;
                    acc = fmaf(dd, dd, acc);
                }
              }
        }
    }
    dist[tid] = (tid < NCAND) ? acc : __int_as_float(0x7f800000);
    __syncthreads();

    // ---- Top-10 smallest of 243 (wave 0): 10x packed wave-argmin + slot kill ----
    if (tid < 64) {
        float sumk = 0.0f;
        #pragma unroll 1
        for (int k = 0; k < KK; k++) {
            unsigned key = 0xFFFFFFFFu;
            #pragma unroll
            for (int j = 0; j < 4; j++) {
                int slot = tid + j*64;
                unsigned b = __float_as_uint(dist[slot]);  // non-neg: bits order-preserving
                unsigned pk = (b & 0xFFFFFF00u) | (unsigned)slot;
                key = min(key, pk);
            }
            #pragma unroll
            for (int ofs = 1; ofs < 64; ofs <<= 1)
                key = min(key, (unsigned)__shfl_xor((int)key, ofs, 64));
            int slot = (int)(key & 0xFFu);
            sumk += dist[slot];                 // exact value, uniform broadcast read
            if (tid == 0) dist[slot] = __int_as_float(0x7f800000);  // kill this instance
        }
        if (tid == 0) ws[q] = sumk;
    }
}

__global__ __launch_bounds__(1024) void reduce_kernel(
    const float* __restrict__ ws, float* __restrict__ out)
{
    __shared__ float sdata[1024];
    float s = 0.0f;
    for (int i = threadIdx.x; i < NQ_; i += 1024) s += ws[i];
    sdata[threadIdx.x] = s;
    __syncthreads();
    for (int ofs = 512; ofs > 0; ofs >>= 1) {
        if ((int)threadIdx.x < ofs) sdata[threadIdx.x] += sdata[threadIdx.x + ofs];
        __syncthreads();
    }
    if (threadIdx.x == 0) out[0] = sdata[0] * (1.0f / (float)(NQ_ * KK));
}

extern "C" void kernel_launch(void* const* d_in, const int* in_sizes, int n_in,
                              void* d_out, int out_size, void* d_ws, size_t ws_size,
                              hipStream_t stream) {
    const float* noisy = (const float*)d_in[0];
    // d_in[1] = deno: unused (SEARCH_INPUT='noisy', refine also uses noisy)
    const float* fflow = (const float*)d_in[2];
    const float* bflow = (const float*)d_in[3];
    float* ws  = (float*)d_ws;
    float* out = (float*)d_out;

    nls_kernel<<<NQ_, 256, 0, stream>>>(noisy, fflow, bflow, ws);
    reduce_kernel<<<1, 1024, 0, stream>>>(ws, out);
}

// Round 2
// 285.564 us; speedup vs baseline: 1.7299x; 1.7299x over previous
//
#include <hip/hip_runtime.h>

#define TT 5
#define HH 384
#define WW 384
#define CC 3
#define PS_ 7
#define WSR 4
#define NH_ 96
#define NW_ 96
#define NQ_ (TT*NH_*NW_)   // 46080
#define NCAND 243
#define KK 10

typedef _Float16 h2v __attribute__((ext_vector_type(2)));
union U32H2 { unsigned u; h2v h; };

// One block (256 threads) per query.
// LDS region layout (packed f16, dwords): [di][c][row][16]
//   dwords 0..7  (copy A): dword j = cols (2j, 2j+1)
//   dwords 8..15 (copy B): dword j-8 = cols (2j-16+1, 2j-16+2)
// Both edge-clamped, so candidate indexing needs no border path.
__global__ __launch_bounds__(256) void nls_kernel(
    const float* __restrict__ vid,    // noisy [T,C,H,W]
    const float* __restrict__ fflow,  // [T,2,H,W], ch0=x/w, ch1=y/h
    const float* __restrict__ bflow,
    float* __restrict__ ws)           // [NQ_] per-query top-K sums
{
    const int q   = blockIdx.x;
    const int tid = threadIdx.x;
    const int t   = q / (NH_*NW_);
    const int rem = q % (NH_*NW_);
    const int hi  = (rem / NW_) * 4;
    const int wi  = (rem % NW_) * 4;

    __shared__ unsigned reg_lds[2160];  // 3di*3c*15r*16 dwords (A+B copies)
    __shared__ unsigned qp_lds[84];     // 3c*7dy*4 dwords, last half of each row = 0
    __shared__ float dist[256];

    // Flow at the query point
    const float ffx = fflow[((t*2+0)*HH + hi)*WW + wi];
    const float ffy = fflow[((t*2+1)*HH + hi)*WW + wi];
    const float bfx = bflow[((t*2+0)*HH + hi)*WW + wi];
    const float bfy = bflow[((t*2+1)*HH + hi)*WW + wi];

    // dt order: [-1 (bflow), 0, +1 (fflow)]
    const int tj0 = (t-1 < 0) ? 0 : (t-1);
    const int tj2 = (t+1 > TT-1) ? (TT-1) : (t+1);
    const int bh0 = min(max(hi + (int)rintf(bfy), 0), HH-1);
    const int bw0 = min(max(wi + (int)rintf(bfx), 0), WW-1);
    const int bh2 = min(max(hi + (int)rintf(ffy), 0), HH-1);
    const int bw2 = min(max(wi + (int)rintf(ffx), 0), WW-1);
    const int rm0 = max(bh0-WSR, 0), cm0 = max(bw0-WSR, 0);
    const int rm1 = max(hi -WSR, 0), cm1 = max(wi -WSR, 0);
    const int rm2 = max(bh2-WSR, 0), cm2 = max(bw2-WSR, 0);

    // ---- Stage region (f16 packed, dual copies) ----
    for (int i = tid; i < 2160; i += 256) {
        int d  = i / 720;
        int rr = i % 720;
        int c  = rr / 240;
        int r2 = rr % 240;
        int r  = r2 >> 4;
        int k  = r2 & 15;
        int tjd = (d==0) ? tj0 : ((d==1) ? t   : tj2);
        int rm  = (d==0) ? rm0 : ((d==1) ? rm1 : rm2);
        int cm  = (d==0) ? cm0 : ((d==1) ? cm1 : cm2);
        int col0 = (k < 8) ? (2*k) : (2*(k-8)+1);
        int row  = min(rm + r, HH-1);
        const float* vrow = vid + (size_t)((tjd*CC + c)*HH + row)*WW;
        float v0 = vrow[min(cm+col0,   WW-1)];
        float v1 = vrow[min(cm+col0+1, WW-1)];
        U32H2 u; u.h.x = (_Float16)v0; u.h.y = (_Float16)v1;
        reg_lds[i] = u.u;
    }
    // ---- Stage query patch (f16 packed, half 7 of each row zeroed) ----
    if (tid < 84) {
        int c  = tid / 28;
        int rr = tid % 28;
        int dy = rr >> 2;
        int k  = rr & 3;
        int row = min(hi+dy, HH-1);
        const float* vrow = vid + (size_t)((t*CC + c)*HH + row)*WW;
        float v0 = vrow[min(wi + 2*k, WW-1)];
        float v1 = (k==3) ? 0.0f : vrow[min(wi + 2*k + 1, WW-1)];
        U32H2 u; u.h.x = (_Float16)v0; u.h.y = (_Float16)v1;
        qp_lds[tid] = u.u;
    }
    __syncthreads();

    // ---- Each of 243 threads: one candidate distance ----
    float acc = 0.0f;
    if (tid < NCAND) {
        int di = tid / 81;
        int s  = tid % 81;
        int sy = s / 9 - WSR;
        int sx = s % 9 - WSR;
        int bhd = (di==0) ? bh0 : ((di==1) ? hi : bh2);
        int bwd = (di==0) ? bw0 : ((di==1) ? wi : bw2);
        int rm  = (di==0) ? rm0 : ((di==1) ? rm1 : rm2);
        int cm  = (di==0) ? cm0 : ((di==1) ? cm1 : cm2);
        int hj = min(max(bhd + sy, 0), HH-1);
        int wj = min(max(bwd + sx, 0), WW-1);
        int roff = hj - rm;              // 0..8
        int woff = wj - cm;              // 0..8
        int par  = woff & 1;
        int cb   = (woff >> 1) + (par << 3);   // A-dwords or B-dwords
        const unsigned* rbase = reg_lds + ((di*3*15 + roff)*16 + cb);
        #pragma unroll
        for (int c = 0; c < CC; c++) {
            const unsigned* rc = rbase + c*240;       // 15*16 dwords per channel
            #pragma unroll
            for (int dy = 0; dy < PS_; dy++) {
                #pragma unroll
                for (int k = 0; k < 4; k++) {
                    U32H2 a, b, d;
                    a.u = rc[dy*16 + k];              // immediate offsets -> ds_read2 fusion
                    b.u = qp_lds[c*28 + dy*4 + k];
                    d.h = a.h - b.h;                  // v_pk_add_f16
                    if (k == 3) d.u &= 0x0000FFFFu;   // kill garbage high half
#if defined(__has_builtin) && __has_builtin(__builtin_amdgcn_fdot2)
                    acc = __builtin_amdgcn_fdot2(d.h, d.h, acc, false);
#else
                    acc += (float)d.h.x*(float)d.h.x + (float)d.h.y*(float)d.h.y;
#endif
                }
            }
        }
    }
    dist[tid] = (tid < NCAND) ? acc : __int_as_float(0x7f800000);
    __syncthreads();

    // ---- Top-10 smallest of 243 (wave 0): 10x packed wave-argmin + slot kill ----
    if (tid < 64) {
        float sumk = 0.0f;
        #pragma unroll 1
        for (int k = 0; k < KK; k++) {
            unsigned key = 0xFFFFFFFFu;
            #pragma unroll
            for (int j = 0; j < 4; j++) {
                int slot = tid + j*64;
                unsigned b = __float_as_uint(dist[slot]);  // non-neg: bits order-preserving
                unsigned pk = (b & 0xFFFFFF00u) | (unsigned)slot;
                key = min(key, pk);
            }
            #pragma unroll
            for (int ofs = 1; ofs < 64; ofs <<= 1)
                key = min(key, (unsigned)__shfl_xor((int)key, ofs, 64));
            int slot = (int)(key & 0xFFu);
            sumk += dist[slot];
            if (tid == 0) dist[slot] = __int_as_float(0x7f800000);
        }
        if (tid == 0) ws[q] = sumk;
    }
}

__global__ __launch_bounds__(1024) void reduce_kernel(
    const float* __restrict__ ws, float* __restrict__ out)
{
    __shared__ float sdata[1024];
    float s = 0.0f;
    for (int i = threadIdx.x; i < NQ_; i += 1024) s += ws[i];
    sdata[threadIdx.x] = s;
    __syncthreads();
    for (int ofs = 512; ofs > 0; ofs >>= 1) {
        if ((int)threadIdx.x < ofs) sdata[threadIdx.x] += sdata[threadIdx.x + ofs];
        __syncthreads();
    }
    if (threadIdx.x == 0) out[0] = sdata[0] * (1.0f / (float)(NQ_ * KK));
}

extern "C" void kernel_launch(void* const* d_in, const int* in_sizes, int n_in,
                              void* d_out, int out_size, void* d_ws, size_t ws_size,
                              hipStream_t stream) {
    const float* noisy = (const float*)d_in[0];
    // d_in[1] = deno: unused (SEARCH_INPUT='noisy', refine also uses noisy)
    const float* fflow = (const float*)d_in[2];
    const float* bflow = (const float*)d_in[3];
    float* ws  = (float*)d_ws;
    float* out = (float*)d_out;

    nls_kernel<<<NQ_, 256, 0, stream>>>(noisy, fflow, bflow, ws);
    reduce_kernel<<<1, 1024, 0, stream>>>(ws, out);
}